// Round 2
// baseline (9296.338 us; speedup 1.0000x reference)
//
#include <hip/hip_runtime.h>
#include <cstdint>
#include <cstddef>

// Problem: B=256, T=512, D=64, H=256, G=4H=1024. 2-layer LSTM + FC head.
// Chunked pipeline over T (TCH=64): gemm0(c) -> rec0(c) -> gemm1(c) -> rec1(c).
// Keeps workspace at ~61 MB (round-0 monolithic layout needed 355 MB -> suspected
// ws overflow -> device abort). All LDS tiles now __align__(16) for b128 DS ops.
#define GATES 1024
#define SEQT  512
#define TCH   64

using u16 = unsigned short;
using bf16x8 = __attribute__((ext_vector_type(8))) short;   // 8 bf16 = 4 VGPRs
using f32x4  = __attribute__((ext_vector_type(4))) float;   // 4 fp32

__device__ __forceinline__ float bf2f(u16 u) {
    union { float f; unsigned int i; } v; v.i = ((unsigned int)u) << 16; return v.f;
}
__device__ __forceinline__ u16 f2bf(float f) {
    union { float f; unsigned int i; } v; v.f = f;
    unsigned int r = v.i + 0x7FFFu + ((v.i >> 16) & 1u);   // RNE
    return (u16)(r >> 16);
}
__device__ __forceinline__ float sigm(float x) { return 1.f / (1.f + __expf(-x)); }
__device__ __forceinline__ float tanh_f(float x) {
    float e = __expf(-2.f * fabsf(x));
    float t = (1.f - e) / (1.f + e);
    return x >= 0.f ? t : -t;
}

// ---------------- prep kernels ----------------
__global__ void k_conv(const float* __restrict__ src, u16* __restrict__ dst, int n) {
    int i = blockIdx.x * 256 + threadIdx.x;
    if (i < n) dst[i] = f2bf(src[i]);
}
__global__ void k_bias(const float* __restrict__ a, const float* __restrict__ b,
                       float* __restrict__ o, int n) {
    int i = blockIdx.x * 256 + threadIdx.x;
    if (i < n) o[i] = a[i] + b[i];
}

// ---------------- chunk GEMM: out[256*TCH,1024] = A_rows @ W[1024,K]^T + bias ---
// A is [B][At_stride][K]; chunk row r -> (b = r/TCH, t = At_off + r%TCH).
// 128x128 tile, 256 threads = 4 waves (2x2), mfma 16x16x32 bf16, padded LDS.
__global__ __launch_bounds__(256, 2) void gemm_xp(
    const u16* __restrict__ A, const u16* __restrict__ W,
    const float* __restrict__ bias, u16* __restrict__ out,
    int K, int At_stride, int At_off)
{
    __shared__ __align__(16) u16 As[128][40];   // +8 pad: <=2-way conflicts
    __shared__ __align__(16) u16 Bs[128][40];
    const int tid  = threadIdx.x;
    const int bid  = blockIdx.x;
    const int mb   = bid >> 3, nb = bid & 7;    // 8 N-tiles
    const int m0   = mb * 128, n0 = nb * 128;
    const int wave = tid >> 6, lane = tid & 63;
    const int wm   = wave >> 1, wn = wave & 1;
    const int ml   = lane & 15, q = lane >> 4;

    f32x4 acc[4][4];
    #pragma unroll
    for (int mi = 0; mi < 4; ++mi)
        #pragma unroll
        for (int ni = 0; ni < 4; ++ni)
            acc[mi][ni] = (f32x4)0.f;

    const int nk = K >> 5;
    for (int kt = 0; kt < nk; ++kt) {
        __syncthreads();
        #pragma unroll
        for (int i = 0; i < 2; ++i) {
            int c = tid + i * 256;
            int row = c >> 2, kb = c & 3;
            int r = m0 + row;
            int b = r / TCH, tl = r % TCH;
            *(uint4*)&As[row][kb * 8] = *(const uint4*)(
                A + ((size_t)b * At_stride + At_off + tl) * K + kt * 32 + kb * 8);
            *(uint4*)&Bs[row][kb * 8] = *(const uint4*)(
                W + (size_t)(n0 + row) * K + kt * 32 + kb * 8);
        }
        __syncthreads();
        bf16x8 af[4], bfr[4];
        #pragma unroll
        for (int mi = 0; mi < 4; ++mi)
            af[mi] = *(const bf16x8*)&As[wm * 64 + mi * 16 + ml][q * 8];
        #pragma unroll
        for (int ni = 0; ni < 4; ++ni)
            bfr[ni] = *(const bf16x8*)&Bs[wn * 64 + ni * 16 + ml][q * 8];
        #pragma unroll
        for (int mi = 0; mi < 4; ++mi)
            #pragma unroll
            for (int ni = 0; ni < 4; ++ni)
                acc[mi][ni] = __builtin_amdgcn_mfma_f32_16x16x32_bf16(
                    af[mi], bfr[ni], acc[mi][ni], 0, 0, 0);
    }

    // C/D layout: col=lane&15, row=q*4+reg
    #pragma unroll
    for (int ni = 0; ni < 4; ++ni) {
        int gc = n0 + wn * 64 + ni * 16 + ml;
        float bv = bias[gc];
        #pragma unroll
        for (int mi = 0; mi < 4; ++mi) {
            int gr = m0 + wm * 64 + mi * 16 + q * 4;
            #pragma unroll
            for (int r = 0; r < 4; ++r)
                out[(size_t)(gr + r) * GATES + gc] = f2bf(acc[mi][ni][r] + bv);
        }
    }
}

// ---------------- LSTM recurrence (one TCH-step chunk) ----------------
// 16 blocks x 512 threads (8 waves). Block owns 16 batch elems; wave w owns
// hidden units [w*32,w*32+32). c-state in registers, h via LDS. W_hh streamed
// from L2 as B-fragments, register-double-buffered. State persists in global
// h_state (bf16) / c_state (f32) between chunk launches.
__global__ __launch_bounds__(512, 2) void lstm_rec(
    const u16* __restrict__ xp,      // chunk [B][TCH][1024], bias folded
    const u16* __restrict__ W,       // [1024][256] bf16
    u16* __restrict__ hseq,          // layer0: chunk [B][TCH][256], else null
    float* __restrict__ hlast,       // layer1: [B][256] at global t=511
    u16* __restrict__ h_state, float* __restrict__ c_state,
    int init, int t0)
{
    __shared__ __align__(16) u16 hA[16][264];   // 528 B row stride
    const int tid  = threadIdx.x;
    const int wave = tid >> 6, lane = tid & 63;
    const int ml   = lane & 15, q = lane >> 4;
    const int ub   = wave * 32;
    const int bb0  = blockIdx.x * 16;

    float c_[8];
    if (init) {
        for (int i = tid; i < 16 * 264; i += 512) ((u16*)hA)[i] = 0;
        #pragma unroll
        for (int i = 0; i < 8; ++i) c_[i] = 0.f;
    } else {
        int m = tid >> 5, j0 = (tid & 31) * 8;   // 512 threads x 8 = 16x256
        *(bf16x8*)&hA[m][j0] = *(const bf16x8*)&h_state[(size_t)(bb0 + m) * 256 + j0];
        #pragma unroll
        for (int s = 0; s < 2; ++s)
            #pragma unroll
            for (int r = 0; r < 4; ++r)
                c_[s * 4 + r] =
                    c_state[(size_t)(bb0 + q * 4 + r) * 256 + ub + s * 16 + ml];
    }

    const u16* wp[8];
    int cols[8];
    #pragma unroll
    for (int gi = 0; gi < 4; ++gi)
        #pragma unroll
        for (int s = 0; s < 2; ++s) {
            int g = gi * 256 + ub + s * 16 + ml;
            wp[gi * 2 + s]   = W + (size_t)g * 256 + q * 8;
            cols[gi * 2 + s] = g;
        }
    size_t xb_[4];
    #pragma unroll
    for (int r = 0; r < 4; ++r)
        xb_[r] = (size_t)(bb0 + q * 4 + r) * TCH * GATES;

    __syncthreads();

    for (int t = 0; t < TCH; ++t) {
        f32x4 acc[4][2];
        #pragma unroll
        for (int gi = 0; gi < 4; ++gi)
            #pragma unroll
            for (int s = 0; s < 2; ++s) {
                f32x4 a;
                #pragma unroll
                for (int r = 0; r < 4; ++r)
                    a[r] = bf2f(xp[xb_[r] + (size_t)t * GATES + cols[gi * 2 + s]]);
                acc[gi][s] = a;
            }

        bf16x8 bcur[8], bnxt[8];
        #pragma unroll
        for (int f = 0; f < 8; ++f) bcur[f] = *(const bf16x8*)(wp[f]);
        #pragma unroll
        for (int k = 0; k < 8; ++k) {
            bf16x8 a = *(const bf16x8*)&hA[ml][k * 32 + q * 8];
            if (k < 7) {
                #pragma unroll
                for (int f = 0; f < 8; ++f)
                    bnxt[f] = *(const bf16x8*)(wp[f] + (k + 1) * 32);
            }
            #pragma unroll
            for (int gi = 0; gi < 4; ++gi)
                #pragma unroll
                for (int s = 0; s < 2; ++s)
                    acc[gi][s] = __builtin_amdgcn_mfma_f32_16x16x32_bf16(
                        a, bcur[gi * 2 + s], acc[gi][s], 0, 0, 0);
            #pragma unroll
            for (int f = 0; f < 8; ++f) bcur[f] = bnxt[f];
        }
        __syncthreads();   // all waves done reading hA for step t

        #pragma unroll
        for (int s = 0; s < 2; ++s) {
            int j = ub + s * 16 + ml;
            #pragma unroll
            for (int r = 0; r < 4; ++r) {
                int m = q * 4 + r;
                float ig = sigm(acc[0][s][r]);
                float fg = sigm(acc[1][s][r]);
                float gg = tanh_f(acc[2][s][r]);
                float og = sigm(acc[3][s][r]);
                float cc = fg * c_[s * 4 + r] + ig * gg;
                c_[s * 4 + r] = cc;
                float h = og * tanh_f(cc);
                u16 hb = f2bf(h);
                hA[m][j] = hb;
                if (hseq)
                    hseq[((size_t)(bb0 + m) * TCH + t) * 256 + j] = hb;
                if (hlast && t0 + t == SEQT - 1)
                    hlast[(size_t)(bb0 + m) * 256 + j] = h;
            }
        }
        __syncthreads();   // h published for step t+1
    }

    // persist state for next chunk
    #pragma unroll
    for (int s = 0; s < 2; ++s)
        #pragma unroll
        for (int r = 0; r < 4; ++r)
            c_state[(size_t)(bb0 + q * 4 + r) * 256 + ub + s * 16 + ml] = c_[s * 4 + r];
    {
        int m = tid >> 5, j0 = (tid & 31) * 8;
        *(bf16x8*)&h_state[(size_t)(bb0 + m) * 256 + j0] = *(const bf16x8*)&hA[m][j0];
    }
}

// ---------------- final FC: out[b] = h1_last[b,:] . fc_w + fc_b ----------------
__global__ void fc_k(const float* __restrict__ h, const float* __restrict__ w,
                     const float* __restrict__ b, float* __restrict__ out)
{
    int bb = blockIdx.x, lane = threadIdx.x;
    float s = 0.f;
    for (int j = lane; j < 256; j += 64) s += h[bb * 256 + j] * w[j];
    #pragma unroll
    for (int off = 32; off > 0; off >>= 1) s += __shfl_down(s, off);
    if (lane == 0) out[bb] = s + b[0];
}

extern "C" void kernel_launch(void* const* d_in, const int* in_sizes, int n_in,
                              void* d_out, int out_size, void* d_ws, size_t ws_size,
                              hipStream_t stream)
{
    const float* x    = (const float*)d_in[0];
    const float* Wih0 = (const float*)d_in[1];
    const float* Whh0 = (const float*)d_in[2];
    const float* bih0 = (const float*)d_in[3];
    const float* bhh0 = (const float*)d_in[4];
    const float* Wih1 = (const float*)d_in[5];
    const float* Whh1 = (const float*)d_in[6];
    const float* bih1 = (const float*)d_in[7];
    const float* bhh1 = (const float*)d_in[8];
    const float* fcw  = (const float*)d_in[9];
    const float* fcb  = (const float*)d_in[10];
    float* out = (float*)d_out;

    // workspace layout (bytes), total ~61.5 MB
    char* ws = (char*)d_ws;
    u16*   xpc   = (u16*)(ws);                  // 256*64*1024*2 = 33554432
    u16*   h0c   = (u16*)(ws + 33554432);       // 256*64*256*2  =  8388608
    u16*   xb    = (u16*)(ws + 41943040);       // 8388608*2     = 16777216
    u16*   Wih0b = (u16*)(ws + 58720256);       // 131072
    u16*   Whh0b = (u16*)(ws + 58851328);       // 524288
    u16*   Wih1b = (u16*)(ws + 59375616);       // 524288
    u16*   Whh1b = (u16*)(ws + 59899904);       // 524288
    float* bias0 = (float*)(ws + 60424192);     // 4096
    float* bias1 = (float*)(ws + 60428288);     // 4096
    u16*   hs0   = (u16*)(ws + 60432384);       // 131072
    float* cs0   = (float*)(ws + 60563456);     // 262144
    u16*   hs1   = (u16*)(ws + 60825600);       // 131072
    float* cs1   = (float*)(ws + 60956672);     // 262144
    float* h1l   = (float*)(ws + 61218816);     // 262144

    // prep: bf16 conversions + bias sums
    k_conv<<<32768, 256, 0, stream>>>(x, xb, 8388608);
    k_conv<<<256,   256, 0, stream>>>(Wih0, Wih0b, 65536);
    k_conv<<<1024,  256, 0, stream>>>(Whh0, Whh0b, 262144);
    k_conv<<<1024,  256, 0, stream>>>(Wih1, Wih1b, 262144);
    k_conv<<<1024,  256, 0, stream>>>(Whh1, Whh1b, 262144);
    k_bias<<<4, 256, 0, stream>>>(bih0, bhh0, bias0, 1024);
    k_bias<<<4, 256, 0, stream>>>(bih1, bhh1, bias1, 1024);

    // chunked two-layer pipeline: 8 chunks x 64 steps
    for (int c = 0; c < SEQT / TCH; ++c) {
        int t0 = c * TCH;
        // layer 0 input projection for this chunk: A = xb [B][512][64], K=64
        gemm_xp<<<1024, 256, 0, stream>>>(xb, Wih0b, bias0, xpc, 64, SEQT, t0);
        lstm_rec<<<16, 512, 0, stream>>>(xpc, Whh0b, h0c, nullptr,
                                         hs0, cs0, c == 0 ? 1 : 0, t0);
        // layer 1 input projection: A = h0c chunk [B][TCH][256], K=256
        gemm_xp<<<1024, 256, 0, stream>>>(h0c, Wih1b, bias1, xpc, 256, TCH, 0);
        lstm_rec<<<16, 512, 0, stream>>>(xpc, Whh1b, nullptr, h1l,
                                         hs1, cs1, c == 0 ? 1 : 0, t0);
    }
    // FC head
    fc_k<<<256, 64, 0, stream>>>(h1l, fcw, fcb, out);
}

// Round 4
// 7676.549 us; speedup vs baseline: 1.2110x; 1.2110x over previous
//
#include <hip/hip_runtime.h>
#include <cstdint>
#include <cstddef>

// B=256, T=512, D=64, H=256, G=1024. Two-layer LSTM + FC.
// TCH=32 chunks; per iteration one fused gemm dispatch (both layers) and one
// fused rec dispatch (layer0 chunk i on blocks 0-15, layer1 chunk i-1 on 16-31).
// xp stored in "rec order": per (t, blk, tid) one contiguous 64 B run of the
// 32 gate-init values that rec lane needs -> 4 coalesced dwordx4 loads/step.
// R3 bug: xp step stride was 16384 (one block) instead of 262144 (full step).
#define GATES 1024
#define SEQT  512
#define TCH   32
#define NCH   16
#define XPSTEP 262144   // elements per timestep in rec-order xp: 16*512*32

using u16 = unsigned short;
using bf16x8 = __attribute__((ext_vector_type(8))) short;   // 8 bf16 = 4 VGPRs
using f32x4  = __attribute__((ext_vector_type(4))) float;

__device__ __forceinline__ float bf2f(u16 u) {
    union { float f; unsigned int i; } v; v.i = ((unsigned int)u) << 16; return v.f;
}
__device__ __forceinline__ u16 f2bf(float f) {
    union { float f; unsigned int i; } v; v.f = f;
    unsigned int r = v.i + 0x7FFFu + ((v.i >> 16) & 1u);   // RNE
    return (u16)(r >> 16);
}
// overflow-safe fast activations (v_exp + v_rcp, ~1 ulp; tolerance headroom 4x)
__device__ __forceinline__ float sigm(float x) {
    return __builtin_amdgcn_rcpf(1.f + __expf(-x));
}
__device__ __forceinline__ float tanh_f(float x) {
    return 1.f - 2.f * __builtin_amdgcn_rcpf(1.f + __expf(2.f * x));
}

// ---------------- prep ----------------
__global__ void k_conv(const float* __restrict__ src, u16* __restrict__ dst, int n) {
    int i = blockIdx.x * 256 + threadIdx.x;
    if (i < n) dst[i] = f2bf(src[i]);
}
__global__ void k_bias(const float* __restrict__ a, const float* __restrict__ b,
                       float* __restrict__ o, int n) {
    int i = blockIdx.x * 256 + threadIdx.x;
    if (i < n) o[i] = a[i] + b[i];
}

// ---------------- fused input-projection GEMM ----------------
// blocks 0-511: layer0 (A=xb [256][512][64], K=64, t_glob = t0+tloc)
// blocks 512-1023: layer1 (A=h0c [32][256][256], K=256)
// Output scattered to rec-order: el = ((tloc*16+blk)*512 + w*64+qr*16+mlr)*32
//                                     + gi*8 + s*4 + r_r
__global__ __launch_bounds__(256, 2) void gemm_fused(
    const u16* __restrict__ A0, const u16* __restrict__ W0,
    const float* __restrict__ b0, u16* __restrict__ o0, int t00,
    const u16* __restrict__ A1, const u16* __restrict__ W1,
    const float* __restrict__ b1, u16* __restrict__ o1, int it)
{
    const int half = blockIdx.x >> 9;
    if (half == 0 && it >= NCH) return;
    if (half == 1 && it == 0) return;
    const int bid = blockIdx.x & 511;

    const u16* A; const u16* W; const float* bias; u16* out;
    int K, As_b, As_t, t0;
    if (half == 0) { A = A0; W = W0; bias = b0; out = o0; K = 64;  As_b = 32768; As_t = 64;    t0 = t00; }
    else           { A = A1; W = W1; bias = b1; out = o1; K = 256; As_b = 256;   As_t = 65536; t0 = 0;   }

    __shared__ __align__(16) u16 As[128][40];
    __shared__ __align__(16) u16 Bs[128][40];
    const int tid  = threadIdx.x;
    const int mb   = bid >> 3, nb = bid & 7;
    const int n0   = nb * 128;
    const int wave = tid >> 6, lane = tid & 63;
    const int wm   = wave >> 1, wn = wave & 1;
    const int ml   = lane & 15, q = lane >> 4;
    const int tloc = mb >> 1;                 // 0..31
    const int tt   = t0 + tloc;
    const int bbas = (mb & 1) * 128;

    f32x4 acc[4][4];
    #pragma unroll
    for (int mi = 0; mi < 4; ++mi)
        #pragma unroll
        for (int ni = 0; ni < 4; ++ni)
            acc[mi][ni] = (f32x4)0.f;

    const int nk = K >> 5;
    for (int kt = 0; kt < nk; ++kt) {
        __syncthreads();
        #pragma unroll
        for (int i = 0; i < 2; ++i) {
            int c = tid + i * 256;
            int row = c >> 2, kb = c & 3;
            *(uint4*)&As[row][kb * 8] = *(const uint4*)(
                A + (size_t)(bbas + row) * As_b + (size_t)tt * As_t + kt * 32 + kb * 8);
            *(uint4*)&Bs[row][kb * 8] = *(const uint4*)(
                W + (size_t)(n0 + row) * K + kt * 32 + kb * 8);
        }
        __syncthreads();
        bf16x8 af[4], bfr[4];
        #pragma unroll
        for (int mi = 0; mi < 4; ++mi)
            af[mi] = *(const bf16x8*)&As[wm * 64 + mi * 16 + ml][q * 8];
        #pragma unroll
        for (int ni = 0; ni < 4; ++ni)
            bfr[ni] = *(const bf16x8*)&Bs[wn * 64 + ni * 16 + ml][q * 8];
        #pragma unroll
        for (int mi = 0; mi < 4; ++mi)
            #pragma unroll
            for (int ni = 0; ni < 4; ++ni)
                acc[mi][ni] = __builtin_amdgcn_mfma_f32_16x16x32_bf16(
                    af[mi], bfr[ni], acc[mi][ni], 0, 0, 0);
    }

    // epilogue: scatter to rec-order
    #pragma unroll
    for (int ni = 0; ni < 4; ++ni) {
        int gc = n0 + wn * 64 + ni * 16 + ml;
        int gi = gc >> 8, u = gc & 255;
        int w = u >> 5, s = (u >> 4) & 1, mlr = u & 15;
        float bv = bias[gc];
        #pragma unroll
        for (int mi = 0; mi < 4; ++mi) {
            int b0r = bbas + wm * 64 + mi * 16 + q * 4;
            #pragma unroll
            for (int rr = 0; rr < 4; ++rr) {
                int bb = b0r + rr;
                int blk = bb >> 4, qr = (bb >> 2) & 3, r_r = bb & 3;
                size_t el = ((size_t)((tloc * 16 + blk) * 512 + w * 64 + qr * 16 + mlr)) * 32
                            + gi * 8 + s * 4 + r_r;
                out[el] = f2bf(acc[mi][ni][rr] + bv);
            }
        }
    }
}

// ---------------- fused LSTM recurrence (one TCH chunk, both layers) -------
// Blocks 0-15: layer0 chunk it; blocks 16-31: layer1 chunk it-1.
// c in regs; h via LDS; W streamed from L2 with depth-4 static reg buffers;
// xp loaded 64 B/lane/step (rec-order), prefetched one step ahead.
__global__ __launch_bounds__(512, 2) void lstm_rec2(
    const u16* __restrict__ xp0, const u16* __restrict__ xp1,
    const u16* __restrict__ W0,  const u16* __restrict__ W1,
    u16* __restrict__ h0c, float* __restrict__ hlast,
    u16* __restrict__ hs0, float* __restrict__ cs0,
    u16* __restrict__ hs1, float* __restrict__ cs1, int it)
{
    const int L   = blockIdx.x >> 4;
    const int blk = blockIdx.x & 15;
    if (L == 0 && it >= NCH) return;
    if (L == 1 && it == 0) return;
    const int chunk = L ? it - 1 : it;
    const u16* xp = L ? xp1 : xp0;
    const u16* W  = L ? W1 : W0;
    u16*  hs = L ? hs1 : hs0;
    float* cs = L ? cs1 : cs0;
    const int init = (chunk == 0);

    __shared__ __align__(16) u16 hA[16][264];
    const int tid  = threadIdx.x;
    const int wave = tid >> 6, lane = tid & 63;
    const int ml   = lane & 15, q = lane >> 4;
    const int ub   = wave * 32;
    const int bb0  = blk * 16;

    float c_[8];
    if (init) {
        for (int i = tid; i < 16 * 264; i += 512) ((u16*)hA)[i] = 0;
        #pragma unroll
        for (int i = 0; i < 8; ++i) c_[i] = 0.f;
    } else {
        int m = tid >> 5, j0 = (tid & 31) * 8;
        *(bf16x8*)&hA[m][j0] = *(const bf16x8*)&hs[(size_t)(bb0 + m) * 256 + j0];
        #pragma unroll
        for (int s = 0; s < 2; ++s)
            #pragma unroll
            for (int r = 0; r < 4; ++r)
                c_[s * 4 + r] = cs[(size_t)(bb0 + q * 4 + r) * 256 + ub + s * 16 + ml];
    }

    int woff_[8];
    #pragma unroll
    for (int gi = 0; gi < 4; ++gi)
        #pragma unroll
        for (int s = 0; s < 2; ++s)
            woff_[gi * 2 + s] = (gi * 256 + ub + s * 16 + ml) * 256 + q * 8;

    // per-lane xp base; step stride XPSTEP elements (16 blocks * 512 thr * 32)
    const u16* xpl = xp + ((size_t)blk * 512 + tid) * 32;

    bf16x8 wb[4][8];
    #pragma unroll
    for (int j = 0; j < 4; ++j)
        #pragma unroll
        for (int f = 0; f < 8; ++f)
            wb[j][f] = *(const bf16x8*)(W + woff_[f] + j * 32);
    bf16x8 xcur[4], xnxt[4];
    #pragma unroll
    for (int gi = 0; gi < 4; ++gi)
        xcur[gi] = *(const bf16x8*)(xpl + gi * 8);

    __syncthreads();

    for (int t = 0; t < TCH; ++t) {
        f32x4 acc[4][2];
        #pragma unroll
        for (int gi = 0; gi < 4; ++gi)
            #pragma unroll
            for (int s = 0; s < 2; ++s)
                #pragma unroll
                for (int r = 0; r < 4; ++r)
                    acc[gi][s][r] = bf2f((u16)xcur[gi][s * 4 + r]);

        int tn = (t + 1 < TCH) ? t + 1 : t;
        #pragma unroll
        for (int gi = 0; gi < 4; ++gi)
            xnxt[gi] = *(const bf16x8*)(xpl + (size_t)tn * XPSTEP + gi * 8);

        #pragma unroll
        for (int k = 0; k < 8; ++k) {
            bf16x8 a = *(const bf16x8*)&hA[ml][k * 32 + q * 8];
            #pragma unroll
            for (int gi = 0; gi < 4; ++gi)
                #pragma unroll
                for (int s = 0; s < 2; ++s)
                    acc[gi][s] = __builtin_amdgcn_mfma_f32_16x16x32_bf16(
                        a, wb[k & 3][gi * 2 + s], acc[gi][s], 0, 0, 0);
            if (k < 4) {
                #pragma unroll
                for (int f = 0; f < 8; ++f)
                    wb[k][f] = *(const bf16x8*)(W + woff_[f] + (k + 4) * 32);
            }
        }
        #pragma unroll
        for (int j = 0; j < 4; ++j)
            #pragma unroll
            for (int f = 0; f < 8; ++f)
                wb[j][f] = *(const bf16x8*)(W + woff_[f] + j * 32);

        __syncthreads();   // all hA reads for step t done

        #pragma unroll
        for (int s = 0; s < 2; ++s) {
            int j = ub + s * 16 + ml;
            #pragma unroll
            for (int r = 0; r < 4; ++r) {
                int m = q * 4 + r;
                float ig = sigm(acc[0][s][r]);
                float fg = sigm(acc[1][s][r]);
                float gg = tanh_f(acc[2][s][r]);
                float og = sigm(acc[3][s][r]);
                float cc = fg * c_[s * 4 + r] + ig * gg;
                c_[s * 4 + r] = cc;
                float h = og * tanh_f(cc);
                u16 hb = f2bf(h);
                hA[m][j] = hb;
                if (L == 0)
                    h0c[((size_t)t * 256 + bb0 + m) * 256 + j] = hb;
                else if (chunk == NCH - 1 && t == TCH - 1)
                    hlast[(size_t)(bb0 + m) * 256 + j] = h;
            }
        }
        #pragma unroll
        for (int gi = 0; gi < 4; ++gi) xcur[gi] = xnxt[gi];
        __syncthreads();   // h(t+1) published
    }

    #pragma unroll
    for (int s = 0; s < 2; ++s)
        #pragma unroll
        for (int r = 0; r < 4; ++r)
            cs[(size_t)(bb0 + q * 4 + r) * 256 + ub + s * 16 + ml] = c_[s * 4 + r];
    {
        int m = tid >> 5, j0 = (tid & 31) * 8;
        *(bf16x8*)&hs[(size_t)(bb0 + m) * 256 + j0] = *(const bf16x8*)&hA[m][j0];
    }
}

// ---------------- FC head ----------------
__global__ void fc_k(const float* __restrict__ h, const float* __restrict__ w,
                     const float* __restrict__ b, float* __restrict__ out)
{
    int bb = blockIdx.x, lane = threadIdx.x;
    float s = 0.f;
    for (int j = lane; j < 256; j += 64) s += h[bb * 256 + j] * w[j];
    #pragma unroll
    for (int off = 32; off > 0; off >>= 1) s += __shfl_down(s, off);
    if (lane == 0) out[bb] = s + b[0];
}

extern "C" void kernel_launch(void* const* d_in, const int* in_sizes, int n_in,
                              void* d_out, int out_size, void* d_ws, size_t ws_size,
                              hipStream_t stream)
{
    const float* x    = (const float*)d_in[0];
    const float* Wih0 = (const float*)d_in[1];
    const float* Whh0 = (const float*)d_in[2];
    const float* bih0 = (const float*)d_in[3];
    const float* bhh0 = (const float*)d_in[4];
    const float* Wih1 = (const float*)d_in[5];
    const float* Whh1 = (const float*)d_in[6];
    const float* bih1 = (const float*)d_in[7];
    const float* bhh1 = (const float*)d_in[8];
    const float* fcw  = (const float*)d_in[9];
    const float* fcb  = (const float*)d_in[10];
    float* out = (float*)d_out;

    // workspace layout, total ~57.3 MB
    char* ws = (char*)d_ws;
    u16*   xp0   = (u16*)(ws);                  // 16777216
    u16*   xp1   = (u16*)(ws + 16777216);       // 16777216
    u16*   h0c   = (u16*)(ws + 33554432);       //  4194304  [32][256][256] bf16
    u16*   xb    = (u16*)(ws + 37748736);       // 16777216  [256][512][64] bf16
    u16*   Wih0b = (u16*)(ws + 54525952);       //   131072
    u16*   Whh0b = (u16*)(ws + 54657024);       //   524288
    u16*   Wih1b = (u16*)(ws + 55181312);       //   524288
    u16*   Whh1b = (u16*)(ws + 55705600);       //   524288
    float* bias0 = (float*)(ws + 56229888);     //     4096
    float* bias1 = (float*)(ws + 56233984);     //     4096
    u16*   hs0   = (u16*)(ws + 56238080);       //   131072
    float* cs0   = (float*)(ws + 56369152);     //   262144
    u16*   hs1   = (u16*)(ws + 56631296);       //   131072
    float* cs1   = (float*)(ws + 56762368);     //   262144
    float* h1l   = (float*)(ws + 57024512);     //   262144

    k_conv<<<32768, 256, 0, stream>>>(x, xb, 8388608);
    k_conv<<<256,   256, 0, stream>>>(Wih0, Wih0b, 65536);
    k_conv<<<1024,  256, 0, stream>>>(Whh0, Whh0b, 262144);
    k_conv<<<1024,  256, 0, stream>>>(Wih1, Wih1b, 262144);
    k_conv<<<1024,  256, 0, stream>>>(Whh1, Whh1b, 262144);
    k_bias<<<4, 256, 0, stream>>>(bih0, bhh0, bias0, 1024);
    k_bias<<<4, 256, 0, stream>>>(bih1, bhh1, bias1, 1024);

    for (int it = 0; it <= NCH; ++it) {
        gemm_fused<<<1024, 256, 0, stream>>>(xb, Wih0b, bias0, xp0, it * TCH,
                                             h0c, Wih1b, bias1, xp1, it);
        lstm_rec2<<<32, 512, 0, stream>>>(xp0, xp1, Whh0b, Whh1b, h0c, h1l,
                                          hs0, cs0, hs1, cs1, it);
    }
    fc_k<<<256, 64, 0, stream>>>(h1l, fcw, fcb, out);
}

// Round 5
// 3073.343 us; speedup vs baseline: 3.0248x; 2.4978x over previous
//
#include <hip/hip_runtime.h>
#include <cstdint>
#include <cstddef>

// B=256, T=512, D=64, H=256, G=1024. Two-layer LSTM + FC.
// TCH=32 chunks; per iteration one fused gemm dispatch (both layers) and one
// fused rec dispatch (layer0 chunk i on blocks 0-15, layer1 chunk i-1 on 16-31).
// R5: W_hh fully CU-resident in the rec kernel: k-frags 0-1 in LDS (128 KB,
// per-wave frag-order), k-frags 2-7 in 192 persistent VGPRs. launch_bounds
// (512,1) for the 256-VGPR budget (R4's (512,2) capped at 128 -> spill storm).
// hA double-buffered -> 1 barrier/step. xp added in cell update (acc starts 0).
#define GATES 1024
#define SEQT  512
#define TCH   32
#define NCH   16
#define XPSTEP 262144   // elements per timestep in rec-order xp: 16*512*32

using u16 = unsigned short;
using bf16x8 = __attribute__((ext_vector_type(8))) short;   // 8 bf16 = 4 VGPRs
using f32x4  = __attribute__((ext_vector_type(4))) float;

__device__ __forceinline__ float bf2f(u16 u) {
    union { float f; unsigned int i; } v; v.i = ((unsigned int)u) << 16; return v.f;
}
__device__ __forceinline__ u16 f2bf(float f) {
    union { float f; unsigned int i; } v; v.f = f;
    unsigned int r = v.i + 0x7FFFu + ((v.i >> 16) & 1u);   // RNE
    return (u16)(r >> 16);
}
// overflow-safe fast activations (v_exp + v_rcp, ~1 ulp)
__device__ __forceinline__ float sigm(float x) {
    return __builtin_amdgcn_rcpf(1.f + __expf(-x));
}
__device__ __forceinline__ float tanh_f(float x) {
    return 1.f - 2.f * __builtin_amdgcn_rcpf(1.f + __expf(2.f * x));
}

// ---------------- prep ----------------
__global__ void k_conv(const float* __restrict__ src, u16* __restrict__ dst, int n) {
    int i = blockIdx.x * 256 + threadIdx.x;
    if (i < n) dst[i] = f2bf(src[i]);
}
__global__ void k_bias(const float* __restrict__ a, const float* __restrict__ b,
                       float* __restrict__ o, int n) {
    int i = blockIdx.x * 256 + threadIdx.x;
    if (i < n) o[i] = a[i] + b[i];
}

// ---------------- fused input-projection GEMM (unchanged from R4) ----------
__global__ __launch_bounds__(256, 2) void gemm_fused(
    const u16* __restrict__ A0, const u16* __restrict__ W0,
    const float* __restrict__ b0, u16* __restrict__ o0, int t00,
    const u16* __restrict__ A1, const u16* __restrict__ W1,
    const float* __restrict__ b1, u16* __restrict__ o1, int it)
{
    const int half = blockIdx.x >> 9;
    if (half == 0 && it >= NCH) return;
    if (half == 1 && it == 0) return;
    const int bid = blockIdx.x & 511;

    const u16* A; const u16* W; const float* bias; u16* out;
    int K, As_b, As_t, t0;
    if (half == 0) { A = A0; W = W0; bias = b0; out = o0; K = 64;  As_b = 32768; As_t = 64;    t0 = t00; }
    else           { A = A1; W = W1; bias = b1; out = o1; K = 256; As_b = 256;   As_t = 65536; t0 = 0;   }

    __shared__ __align__(16) u16 As[128][40];
    __shared__ __align__(16) u16 Bs[128][40];
    const int tid  = threadIdx.x;
    const int mb   = bid >> 3, nb = bid & 7;
    const int n0   = nb * 128;
    const int wave = tid >> 6, lane = tid & 63;
    const int wm   = wave >> 1, wn = wave & 1;
    const int ml   = lane & 15, q = lane >> 4;
    const int tloc = mb >> 1;
    const int tt   = t0 + tloc;
    const int bbas = (mb & 1) * 128;

    f32x4 acc[4][4];
    #pragma unroll
    for (int mi = 0; mi < 4; ++mi)
        #pragma unroll
        for (int ni = 0; ni < 4; ++ni)
            acc[mi][ni] = (f32x4)0.f;

    const int nk = K >> 5;
    for (int kt = 0; kt < nk; ++kt) {
        __syncthreads();
        #pragma unroll
        for (int i = 0; i < 2; ++i) {
            int c = tid + i * 256;
            int row = c >> 2, kb = c & 3;
            *(uint4*)&As[row][kb * 8] = *(const uint4*)(
                A + (size_t)(bbas + row) * As_b + (size_t)tt * As_t + kt * 32 + kb * 8);
            *(uint4*)&Bs[row][kb * 8] = *(const uint4*)(
                W + (size_t)(n0 + row) * K + kt * 32 + kb * 8);
        }
        __syncthreads();
        bf16x8 af[4], bfr[4];
        #pragma unroll
        for (int mi = 0; mi < 4; ++mi)
            af[mi] = *(const bf16x8*)&As[wm * 64 + mi * 16 + ml][q * 8];
        #pragma unroll
        for (int ni = 0; ni < 4; ++ni)
            bfr[ni] = *(const bf16x8*)&Bs[wn * 64 + ni * 16 + ml][q * 8];
        #pragma unroll
        for (int mi = 0; mi < 4; ++mi)
            #pragma unroll
            for (int ni = 0; ni < 4; ++ni)
                acc[mi][ni] = __builtin_amdgcn_mfma_f32_16x16x32_bf16(
                    af[mi], bfr[ni], acc[mi][ni], 0, 0, 0);
    }

    #pragma unroll
    for (int ni = 0; ni < 4; ++ni) {
        int gc = n0 + wn * 64 + ni * 16 + ml;
        int gi = gc >> 8, u = gc & 255;
        int w = u >> 5, s = (u >> 4) & 1, mlr = u & 15;
        float bv = bias[gc];
        #pragma unroll
        for (int mi = 0; mi < 4; ++mi) {
            int b0r = bbas + wm * 64 + mi * 16 + q * 4;
            #pragma unroll
            for (int rr = 0; rr < 4; ++rr) {
                int bb = b0r + rr;
                int blk = bb >> 4, qr = (bb >> 2) & 3, r_r = bb & 3;
                size_t el = ((size_t)((tloc * 16 + blk) * 512 + w * 64 + qr * 16 + mlr)) * 32
                            + gi * 8 + s * 4 + r_r;
                out[el] = f2bf(acc[mi][ni][rr] + bv);
            }
        }
    }
}

// ---------------- fused LSTM recurrence, W fully CU-resident ----------------
// Blocks 0-15: layer0 chunk it; blocks 16-31: layer1 chunk it-1.
// Wave owns 128 gate rows. W k-frags 0-1 staged once into LDS (per-wave
// frag-order, contiguous per lane); k-frags 2-7 live in wreg[6][8] (192 VGPR).
// hA double-buffered: step t reads buf t&1, writes buf (t+1)&1, ONE barrier.
__global__ __launch_bounds__(512, 1) void lstm_rec2(
    const u16* __restrict__ xp0, const u16* __restrict__ xp1,
    const u16* __restrict__ W0,  const u16* __restrict__ W1,
    u16* __restrict__ h0c, float* __restrict__ hlast,
    u16* __restrict__ hs0, float* __restrict__ cs0,
    u16* __restrict__ hs1, float* __restrict__ cs1, int it)
{
    const int L   = blockIdx.x >> 4;
    const int blk = blockIdx.x & 15;
    if (L == 0 && it >= NCH) return;
    if (L == 1 && it == 0) return;
    const int chunk = L ? it - 1 : it;
    const u16* xp = L ? xp1 : xp0;
    const u16* W  = L ? W1 : W0;
    u16*  hs = L ? hs1 : hs0;
    float* cs = L ? cs1 : cs0;
    const int init = (chunk == 0);

    __shared__ __align__(16) u16 WL[8 * 16 * 64 * 8];   // 131072 B, per-wave frag-order
    __shared__ __align__(16) u16 hA[2][16][264];        // 16896 B, double buffer

    const int tid  = threadIdx.x;
    const int wave = tid >> 6, lane = tid & 63;
    const int ml   = lane & 15, q = lane >> 4;
    const int ub   = wave * 32;
    const int bb0  = blk * 16;

    // W fragment element offsets: frag f = gi*2+s -> gate rows g
    int woff_[8];
    #pragma unroll
    for (int gi = 0; gi < 4; ++gi)
        #pragma unroll
        for (int s = 0; s < 2; ++s)
            woff_[gi * 2 + s] = (gi * 256 + ub + s * 16 + ml) * 256 + q * 8;

    // stage W k-frags 0-1 into LDS (each lane round-trips its own 16 B)
    const int wlb = (wave * 1024 + lane) * 8;   // element index of this lane's slot 0
    #pragma unroll
    for (int kf = 0; kf < 2; ++kf)
        #pragma unroll
        for (int f = 0; f < 8; ++f)
            *(bf16x8*)&WL[wlb + (kf * 8 + f) * 512] =
                *(const bf16x8*)(W + woff_[f] + kf * 32);

    // W k-frags 2-7 persistent in registers (192 VGPR)
    bf16x8 wreg[6][8];
    #pragma unroll
    for (int kf = 2; kf < 8; ++kf)
        #pragma unroll
        for (int f = 0; f < 8; ++f)
            wreg[kf - 2][f] = *(const bf16x8*)(W + woff_[f] + kf * 32);

    float c_[8];
    if (init) {
        for (int i = tid; i < 16 * 264; i += 512) ((u16*)&hA[0][0][0])[i] = 0;
        #pragma unroll
        for (int i = 0; i < 8; ++i) c_[i] = 0.f;
    } else {
        int m = tid >> 5, j0 = (tid & 31) * 8;
        *(bf16x8*)&hA[0][m][j0] = *(const bf16x8*)&hs[(size_t)(bb0 + m) * 256 + j0];
        #pragma unroll
        for (int s = 0; s < 2; ++s)
            #pragma unroll
            for (int r = 0; r < 4; ++r)
                c_[s * 4 + r] = cs[(size_t)(bb0 + q * 4 + r) * 256 + ub + s * 16 + ml];
    }

    const u16* xpt = xp + ((size_t)blk * 512 + tid) * 32;   // + t*XPSTEP per step

    __syncthreads();

    for (int t = 0; t < TCH; ++t) {
        const int br = t & 1, bw = br ^ 1;

        // xp for this step: issued now, consumed only in the cell update
        bf16x8 xv[4];
        #pragma unroll
        for (int gi = 0; gi < 4; ++gi)
            xv[gi] = *(const bf16x8*)(xpt + gi * 8);

        f32x4 acc[4][2];
        #pragma unroll
        for (int gi = 0; gi < 4; ++gi)
            #pragma unroll
            for (int s = 0; s < 2; ++s)
                acc[gi][s] = (f32x4)0.f;

        // k-frags 0-1 from LDS
        #pragma unroll
        for (int kf = 0; kf < 2; ++kf) {
            bf16x8 a = *(const bf16x8*)&hA[br][ml][kf * 32 + q * 8];
            #pragma unroll
            for (int f = 0; f < 8; ++f) {
                bf16x8 b = *(const bf16x8*)&WL[wlb + (kf * 8 + f) * 512];
                acc[f >> 1][f & 1] = __builtin_amdgcn_mfma_f32_16x16x32_bf16(
                    a, b, acc[f >> 1][f & 1], 0, 0, 0);
            }
        }
        // k-frags 2-7 from persistent registers
        #pragma unroll
        for (int kf = 2; kf < 8; ++kf) {
            bf16x8 a = *(const bf16x8*)&hA[br][ml][kf * 32 + q * 8];
            #pragma unroll
            for (int f = 0; f < 8; ++f)
                acc[f >> 1][f & 1] = __builtin_amdgcn_mfma_f32_16x16x32_bf16(
                    a, wreg[kf - 2][f], acc[f >> 1][f & 1], 0, 0, 0);
        }

        // cell update: gate pre-activation = acc + xp (bias folded into xp)
        #pragma unroll
        for (int s = 0; s < 2; ++s) {
            int j = ub + s * 16 + ml;
            #pragma unroll
            for (int r = 0; r < 4; ++r) {
                int m = q * 4 + r;
                float ig = sigm(acc[0][s][r] + bf2f((u16)xv[0][s * 4 + r]));
                float fg = sigm(acc[1][s][r] + bf2f((u16)xv[1][s * 4 + r]));
                float gg = tanh_f(acc[2][s][r] + bf2f((u16)xv[2][s * 4 + r]));
                float og = sigm(acc[3][s][r] + bf2f((u16)xv[3][s * 4 + r]));
                float cc = fg * c_[s * 4 + r] + ig * gg;
                c_[s * 4 + r] = cc;
                float h = og * tanh_f(cc);
                u16 hb = f2bf(h);
                hA[bw][m][j] = hb;
                if (L == 0)
                    h0c[((size_t)t * 256 + bb0 + m) * 256 + j] = hb;
                else if (chunk == NCH - 1 && t == TCH - 1)
                    hlast[(size_t)(bb0 + m) * 256 + j] = h;
            }
        }
        xpt += XPSTEP;
        __syncthreads();   // h(t+1) published in buf bw; next step reads it
    }

    // persist state (TCH even -> final h is in buf 0)
    #pragma unroll
    for (int s = 0; s < 2; ++s)
        #pragma unroll
        for (int r = 0; r < 4; ++r)
            cs[(size_t)(bb0 + q * 4 + r) * 256 + ub + s * 16 + ml] = c_[s * 4 + r];
    {
        int m = tid >> 5, j0 = (tid & 31) * 8;
        *(bf16x8*)&hs[(size_t)(bb0 + m) * 256 + j0] = *(const bf16x8*)&hA[0][m][j0];
    }
}

// ---------------- FC head ----------------
__global__ void fc_k(const float* __restrict__ h, const float* __restrict__ w,
                     const float* __restrict__ b, float* __restrict__ out)
{
    int bb = blockIdx.x, lane = threadIdx.x;
    float s = 0.f;
    for (int j = lane; j < 256; j += 64) s += h[bb * 256 + j] * w[j];
    #pragma unroll
    for (int off = 32; off > 0; off >>= 1) s += __shfl_down(s, off);
    if (lane == 0) out[bb] = s + b[0];
}

extern "C" void kernel_launch(void* const* d_in, const int* in_sizes, int n_in,
                              void* d_out, int out_size, void* d_ws, size_t ws_size,
                              hipStream_t stream)
{
    const float* x    = (const float*)d_in[0];
    const float* Wih0 = (const float*)d_in[1];
    const float* Whh0 = (const float*)d_in[2];
    const float* bih0 = (const float*)d_in[3];
    const float* bhh0 = (const float*)d_in[4];
    const float* Wih1 = (const float*)d_in[5];
    const float* Whh1 = (const float*)d_in[6];
    const float* bih1 = (const float*)d_in[7];
    const float* bhh1 = (const float*)d_in[8];
    const float* fcw  = (const float*)d_in[9];
    const float* fcb  = (const float*)d_in[10];
    float* out = (float*)d_out;

    // workspace layout, total ~57.3 MB
    char* ws = (char*)d_ws;
    u16*   xp0   = (u16*)(ws);                  // 16777216
    u16*   xp1   = (u16*)(ws + 16777216);       // 16777216
    u16*   h0c   = (u16*)(ws + 33554432);       //  4194304  [32][256][256] bf16
    u16*   xb    = (u16*)(ws + 37748736);       // 16777216  [256][512][64] bf16
    u16*   Wih0b = (u16*)(ws + 54525952);       //   131072
    u16*   Whh0b = (u16*)(ws + 54657024);       //   524288
    u16*   Wih1b = (u16*)(ws + 55181312);       //   524288
    u16*   Whh1b = (u16*)(ws + 55705600);       //   524288
    float* bias0 = (float*)(ws + 56229888);     //     4096
    float* bias1 = (float*)(ws + 56233984);     //     4096
    u16*   hs0   = (u16*)(ws + 56238080);       //   131072
    float* cs0   = (float*)(ws + 56369152);     //   262144
    u16*   hs1   = (u16*)(ws + 56631296);       //   131072
    float* cs1   = (float*)(ws + 56762368);     //   262144
    float* h1l   = (float*)(ws + 57024512);     //   262144

    k_conv<<<32768, 256, 0, stream>>>(x, xb, 8388608);
    k_conv<<<256,   256, 0, stream>>>(Wih0, Wih0b, 65536);
    k_conv<<<1024,  256, 0, stream>>>(Whh0, Whh0b, 262144);
    k_conv<<<1024,  256, 0, stream>>>(Wih1, Wih1b, 262144);
    k_conv<<<1024,  256, 0, stream>>>(Whh1, Whh1b, 262144);
    k_bias<<<4, 256, 0, stream>>>(bih0, bhh0, bias0, 1024);
    k_bias<<<4, 256, 0, stream>>>(bih1, bhh1, bias1, 1024);

    for (int it = 0; it <= NCH; ++it) {
        gemm_fused<<<1024, 256, 0, stream>>>(xb, Wih0b, bias0, xp0, it * TCH,
                                             h0c, Wih1b, bias1, xp1, it);
        lstm_rec2<<<32, 512, 0, stream>>>(xp0, xp1, Whh0b, Whh1b, h0c, h1l,
                                          hs0, cs0, hs1, cs1, it);
    }
    fc_k<<<256, 64, 0, stream>>>(h1l, fcw, fcb, out);
}